// Round 7
// baseline (218.416 us; speedup 1.0000x reference)
//
#include <hip/hip_runtime.h>

// Forward kinematics, H36M 17-joint skeleton. One thread = one sample.
// R10: persistent blocks + double-buffered DMA pipeline (counted vmcnt).
// R9 post-mortem: coalesced DMA input (FETCH 62.6MB, clean) changed NOTHING
// -> input issue order was never the wall. Invariant across R3-R9: delivered
// BW pins at 2.3-2.9 TB/s vs 6.3 achievable. Cause: burstiness. Each wave's
// memory timeline is [13KB burst] -> vmcnt(0) -> ~2.6k cy compute with ZERO
// bytes in flight -> store burst -> die. Little's law: 6.3 TB/s needs ~9.2KB
// continuously in flight per CU; our time-average is far below. Occupancy
// can't fix it (R7: 2x waves, same BW) -- dead windows are in phase per wave.
// Fix (GEMM T3/T14 pattern): persistent block owns KTILES contiguous tiles,
// two 64x52 LDS buffers; prefetch tile k+1 (4 blen loads THEN 13 DMA, blen
// older so the L-reg copy's implicit waitcnt can't drain the DMA) is issued
// before computing tile k; steady-state wait is vmcnt(17) -- exactly the 17
// prefetch ops stay in flight across compute+drain. vmcnt(0) only on the
// last tile. sched_barrier pins drain stores before the prefetch group so
// the newest-17 accounting holds (compiler defeat = over-wait, still correct).
// LDS 2*64*52*4 = 26624 B -> 6 blocks/CU; compute/drain schemes verbatim R9.

#define NB 64
#define KTILES 5

#define GLB_PTR(x) ((const __attribute__((address_space(1))) void*)(x))
#define LDS_PTR(x) ((__attribute__((address_space(3))) void*)(x))

__device__ __forceinline__ void mm3(const float A[9], const float B[9], float C[9]) {
#pragma unroll
    for (int r = 0; r < 3; ++r) {
        C[3*r+0] = A[3*r+0]*B[0] + A[3*r+1]*B[3] + A[3*r+2]*B[6];
        C[3*r+1] = A[3*r+0]*B[1] + A[3*r+1]*B[4] + A[3*r+2]*B[7];
        C[3*r+2] = A[3*r+0]*B[2] + A[3*r+1]*B[5] + A[3*r+2]*B[8];
    }
}

// R = Rx(a) @ Ry(b) @ Rz(c)  (pytorch3d euler_angles_to_matrix 'XYZ'), row-major
__device__ __forceinline__ void erot(float a, float b, float c, float R[9]) {
    float sx, cx, sy, cy, sz, cz;
    __sincosf(a, &sx, &cx);
    __sincosf(b, &sy, &cy);
    __sincosf(c, &sz, &cz);
    R[0] = cy*cz;             R[1] = -cy*sz;            R[2] = sy;
    R[3] = sx*sy*cz + cx*sz;  R[4] = -sx*sy*sz + cx*cz; R[5] = -sx*cy;
    R[6] = -cx*sy*cz + sx*sz; R[7] = cx*sy*sz + sx*cz;  R[8] = cx*cy;
}

// In-place compute on one sample's 52-word LDS region (R9 scheme, proven):
// inputs (bone i) at words 3i..3i+2; joint j overwrites words 3j..3j+2 only
// after bone j's words were read (e/f alternating read-one-bone-ahead).
__device__ __forceinline__ void compute_tile(float* o, const float* L) {
    float ex, ey, ez, fx, fy, fz;
    float Ma[9], Mb[9], M8[9], R[9];
    float px, py, pz, p8x, p8y, p8z;

    ex = o[0];  ey = o[1];  ez = o[2];    // bone 0
    fx = o[3];  fy = o[4];  fz = o[5];    // bone 1
    o[0] = 0.f; o[1] = 0.f; o[2] = 0.f;   // root

    // chain 0 -> 1 -> 2 -> 3 (bones 0,1,2)
    erot(ex, ey, ez, Ma);
    px = L[0]*Ma[6]; py = L[0]*Ma[7]; pz = L[0]*Ma[8];
    ex = o[6];  ey = o[7];  ez = o[8];    // bone 2
    o[3] = px; o[4] = py; o[5] = pz;
    erot(fx, fy, fz, R); mm3(Ma, R, Mb);
    px += L[1]*Mb[6]; py += L[1]*Mb[7]; pz += L[1]*Mb[8];
    fx = o[9];  fy = o[10]; fz = o[11];   // bone 3
    o[6] = px; o[7] = py; o[8] = pz;
    erot(ex, ey, ez, R); mm3(Mb, R, Ma);
    px += L[2]*Ma[6]; py += L[2]*Ma[7]; pz += L[2]*Ma[8];
    ex = o[12]; ey = o[13]; ez = o[14];   // bone 4
    o[9] = px; o[10] = py; o[11] = pz;

    // chain 0 -> 4 -> 5 -> 6 (bones 3,4,5)
    erot(fx, fy, fz, Ma);
    px = L[3]*Ma[6]; py = L[3]*Ma[7]; pz = L[3]*Ma[8];
    fx = o[15]; fy = o[16]; fz = o[17];   // bone 5
    o[12] = px; o[13] = py; o[14] = pz;
    erot(ex, ey, ez, R); mm3(Ma, R, Mb);
    px += L[4]*Mb[6]; py += L[4]*Mb[7]; pz += L[4]*Mb[8];
    ex = o[18]; ey = o[19]; ez = o[20];   // bone 6
    o[15] = px; o[16] = py; o[17] = pz;
    erot(fx, fy, fz, R); mm3(Mb, R, Ma);
    px += L[5]*Ma[6]; py += L[5]*Ma[7]; pz += L[5]*Ma[8];
    fx = o[21]; fy = o[22]; fz = o[23];   // bone 7
    o[18] = px; o[19] = py; o[20] = pz;

    // spine 0 -> 7 -> 8 (bones 6,7)
    erot(ex, ey, ez, Ma);
    px = L[6]*Ma[6]; py = L[6]*Ma[7]; pz = L[6]*Ma[8];
    ex = o[24]; ey = o[25]; ez = o[26];   // bone 8
    o[21] = px; o[22] = py; o[23] = pz;
    erot(fx, fy, fz, R); mm3(Ma, R, M8);
    px += L[7]*M8[6]; py += L[7]*M8[7]; pz += L[7]*M8[8];
    fx = o[27]; fy = o[28]; fz = o[29];   // bone 9
    o[24] = px; o[25] = py; o[26] = pz;
    p8x = px; p8y = py; p8z = pz;

    // branch 8 -> 9 -> 10 (bones 8,9)
    erot(ex, ey, ez, R); mm3(M8, R, Ma);
    px = p8x + L[8]*Ma[6]; py = p8y + L[8]*Ma[7]; pz = p8z + L[8]*Ma[8];
    ex = o[30]; ey = o[31]; ez = o[32];   // bone 10
    o[27] = px; o[28] = py; o[29] = pz;
    erot(fx, fy, fz, R); mm3(Ma, R, Mb);
    px += L[9]*Mb[6]; py += L[9]*Mb[7]; pz += L[9]*Mb[8];
    fx = o[33]; fy = o[34]; fz = o[35];   // bone 11
    o[30] = px; o[31] = py; o[32] = pz;

    // branch 8 -> 11 -> 12 -> 13 (bones 10,11,12)
    erot(ex, ey, ez, R); mm3(M8, R, Ma);
    px = p8x + L[10]*Ma[6]; py = p8y + L[10]*Ma[7]; pz = p8z + L[10]*Ma[8];
    ex = o[36]; ey = o[37]; ez = o[38];   // bone 12
    o[33] = px; o[34] = py; o[35] = pz;
    erot(fx, fy, fz, R); mm3(Ma, R, Mb);
    px += L[11]*Mb[6]; py += L[11]*Mb[7]; pz += L[11]*Mb[8];
    fx = o[39]; fy = o[40]; fz = o[41];   // bone 13
    o[36] = px; o[37] = py; o[38] = pz;
    erot(ex, ey, ez, R); mm3(Mb, R, Ma);
    px += L[12]*Ma[6]; py += L[12]*Ma[7]; pz += L[12]*Ma[8];
    ex = o[42]; ey = o[43]; ez = o[44];   // bone 14
    o[39] = px; o[40] = py; o[41] = pz;

    // branch 8 -> 14 -> 15 -> 16 (bones 13,14,15)
    erot(fx, fy, fz, R); mm3(M8, R, Ma);
    px = p8x + L[13]*Ma[6]; py = p8y + L[13]*Ma[7]; pz = p8z + L[13]*Ma[8];
    fx = o[45]; fy = o[46]; fz = o[47];   // bone 15
    o[42] = px; o[43] = py; o[44] = pz;
    erot(ex, ey, ez, R); mm3(Ma, R, Mb);
    px += L[14]*Mb[6]; py += L[14]*Mb[7]; pz += L[14]*Mb[8];
    o[45] = px; o[46] = py; o[47] = pz;
    erot(fx, fy, fz, R); mm3(Mb, R, Ma);
    px += L[15]*Ma[6]; py += L[15]*Ma[7]; pz += L[15]*Ma[8];
    o[48] = px; o[49] = py; o[50] = pz;   // pad words, no hazard
}

__global__ void __launch_bounds__(NB)
fk17_kernel(const float* __restrict__ euler, const float* __restrict__ blen,
            float* __restrict__ out, int n, int ntiles, int ktiles)
{
    __shared__ float s_b[2][NB * 52];   // 26624 B -> 6 blocks/CU

    const int tid   = threadIdx.x;
    const int tile0 = blockIdx.x * ktiles;
    if (tile0 >= ntiles) return;
    const int kc = min(ktiles, ntiles - tile0);

    float Lc[16], Ln[16];

    // ---- prologue: stage tile0 into buffer 0 ----
    {
        const int t  = tile0 * NB + tid;
        const int tc = min(t, n - 1);
        const float4* gb4 = (const float4*)(blen + (size_t)tc * 16);
#pragma unroll
        for (int q = 0; q < 4; ++q) {
            float4 v = gb4[q];
            Lc[4*q+0] = v.x; Lc[4*q+1] = v.y; Lc[4*q+2] = v.z; Lc[4*q+3] = v.w;
        }
        const int base = tile0 * NB;
#pragma unroll
        for (int j = 0; j < 13; ++j) {
            int m = j * 64 + tid;
            int s = m / 13;                  // const-div -> magic mul
            int c = m - s * 13;
            if (c == 12) c = 0;              // pad slot: harmless duplicate
            int gs = min(base + s, n - 1);
            __builtin_amdgcn_global_load_lds(
                GLB_PTR(euler + (size_t)gs * 48 + c * 4),
                LDS_PTR(&s_b[0][0] + j * 256), 16, 0, 0);
        }
    }

    for (int i = 0; i < kc; ++i) {
        const int  cur  = i & 1;
        float*     bb   = &s_b[cur][0];
        const int  tile = tile0 + i;
        const bool pf   = (i + 1 < kc);

        // ---- prefetch tile i+1 into the other buffer: 4 blen loads (older)
        //      then 13 DMA (newer) = exactly the 17 newest vmem ops ----
        if (pf) {
            const int t  = (tile + 1) * NB + tid;
            const int tc = min(t, n - 1);
            const float4* gb4 = (const float4*)(blen + (size_t)tc * 16);
#pragma unroll
            for (int q = 0; q < 4; ++q) {
                float4 v = gb4[q];
                Ln[4*q+0] = v.x; Ln[4*q+1] = v.y; Ln[4*q+2] = v.z; Ln[4*q+3] = v.w;
            }
            const int base = (tile + 1) * NB;
            float* nb = &s_b[cur ^ 1][0];
#pragma unroll
            for (int j = 0; j < 13; ++j) {
                int m = j * 64 + tid;
                int s = m / 13;
                int c = m - s * 13;
                if (c == 12) c = 0;
                int gs = min(base + s, n - 1);
                __builtin_amdgcn_global_load_lds(
                    GLB_PTR(euler + (size_t)gs * 48 + c * 4),
                    LDS_PTR(nb + j * 256), 16, 0, 0);
            }
        }

        // ---- counted wait: current tile's staging done, prefetch's 17 ops
        //      (and only those) stay in flight across compute+drain ----
        if (pf) asm volatile("s_waitcnt vmcnt(17)" ::: "memory");
        else    asm volatile("s_waitcnt vmcnt(0)"  ::: "memory");
        __builtin_amdgcn_sched_barrier(0);

        const int nv = min(NB, n - tile * NB);
        if (tid < nv) compute_tile(bb + tid * 52, Lc);

        // ---- drain: LDS (stride 52) -> global (stride 51), lane-consecutive,
        //      each store instr = 256 contiguous bytes, WRITE_SIZE exact ----
        {
            float* og = out + (size_t)tile * NB * 51;
            if (nv == NB) {
#pragma unroll
                for (int k = 0; k < 51; ++k) {
                    int m = tid + 64 * k;
                    int s = m / 51;          // const-div -> magic mul
                    og[m] = bb[m + s];
                }
            } else {
                const int tot = nv * 51;
                for (int m = tid; m < tot; m += NB) {
                    int s = m / 51;
                    og[m] = bb[m + s];
                }
            }
        }
        // pin drain stores BEFORE next iteration's prefetch group so the
        // newest-17 accounting holds
        __builtin_amdgcn_sched_barrier(0);

#pragma unroll
        for (int q = 0; q < 16; ++q) Lc[q] = Ln[q];  // reg copy; implicit
        // waitcnt for Ln only forces the (older) blen loads, not the DMA
    }
}

extern "C" void kernel_launch(void* const* d_in, const int* in_sizes, int n_in,
                              void* d_out, int out_size, void* d_ws, size_t ws_size,
                              hipStream_t stream) {
    const float* euler = (const float*)d_in[0];   // (N,16,3) fp32
    const float* blen  = (const float*)d_in[1];   // (N,16,1) fp32
    float* out = (float*)d_out;                   // (N,17,3) fp32

    const int n      = in_sizes[0] / 48;
    const int ntiles = (n + NB - 1) / NB;
    const int grid   = (ntiles + KTILES - 1) / KTILES;
    fk17_kernel<<<grid, NB, 0, stream>>>(euler, blen, out, n, ntiles, KTILES);
}